// Round 8
// baseline (173.751 us; speedup 1.0000x reference)
//
#include <hip/hip_runtime.h>
#include <hip/hip_bf16.h>

// Problem dims
#define T_DIM 512
#define B_DIM 32
#define IN_DIM 256
#define H_DIM 256
#define K_DIM 10
#define TB 16384          // T*B
#define NKH 2560          // H*K
#define NPOW 3            // normalized power updates (v0 = rsum = M@1 is already 1 step)

typedef __attribute__((ext_vector_type(8))) short short8;
typedef __attribute__((ext_vector_type(4))) float f32x4;

#define GLOBAL_AS __attribute__((address_space(1)))
#define LDS_AS __attribute__((address_space(3)))

__device__ __forceinline__ float wave_sum64(float v) {
    #pragma unroll
    for (int off = 32; off > 0; off >>= 1) v += __shfl_xor(v, off, 64);
    return v;
}

// ---- prep: weight normalize (blocks 0..639) + x norms/bf16 (blocks 640..4735) ----
__global__ __launch_bounds__(256) void prep_kernel(const float* __restrict__ w,
        const float* __restrict__ x, __hip_bfloat16* __restrict__ wb,
        __hip_bfloat16* __restrict__ wb2, float* __restrict__ xninfo,
        __hip_bfloat16* __restrict__ xb) {
    int wv = threadIdx.x >> 6, lane = threadIdx.x & 63;
    if (blockIdx.x < 640) {
        int row = blockIdx.x * 4 + wv;                 // 0..2559  (= h*10+k)
        const float* src = w + (size_t)row * IN_DIM;
        float v[4]; float s = 0.f;
        #pragma unroll
        for (int j = 0; j < 4; ++j) { v[j] = src[lane + 64 * j]; s += v[j] * v[j]; }
        s = wave_sum64(s);
        float inv = 1.f / fmaxf(sqrtf(s), 1e-4f);
        int h = row / K_DIM, k = row % K_DIM;
        __hip_bfloat16* d1 = wb + (size_t)(k * H_DIM + h) * IN_DIM;
        __hip_bfloat16* d2 = wb2 + (size_t)h * NKH + k * IN_DIM;
        #pragma unroll
        for (int j = 0; j < 4; ++j) {
            __hip_bfloat16 t = __float2bfloat16(v[j] * inv);
            d1[lane + 64 * j] = t;
            d2[lane + 64 * j] = t;
        }
    } else {
        int row = (blockIdx.x - 640) * 4 + wv;         // 0..16383
        const float* src = x + (size_t)row * IN_DIM;
        float v[4]; float s = 0.f;
        #pragma unroll
        for (int j = 0; j < 4; ++j) { v[j] = src[lane + 64 * j]; s += v[j] * v[j]; }
        s = wave_sum64(s);
        float nrm = sqrtf(s);
        if (lane == 0) { xninfo[2 * row] = nrm; xninfo[2 * row + 1] = 1.f / fmaxf(nrm, 1e-4f); }
        __hip_bfloat16* d = xb + (size_t)row * IN_DIM;
        #pragma unroll
        for (int j = 0; j < 4; ++j) d[lane + 64 * j] = __float2bfloat16(v[j]);
    }
}

// ---- big GEMM via bf16 MFMA + kappa epilogue -> bmat bf16 [t][b][k][h] ----
__global__ __launch_bounds__(256) void gemm_b_mfma(const __hip_bfloat16* __restrict__ xb,
        const __hip_bfloat16* __restrict__ wb, const float* __restrict__ xninfo,
        __hip_bfloat16* __restrict__ bmat) {
    __shared__ __hip_bfloat16 As[4096];   // [128][32]
    __shared__ __hip_bfloat16 Bs[4096];
    int tid = threadIdx.x;
    int wid = tid >> 6, lane = tid & 63;
    int m0 = blockIdx.x * 128, n0 = blockIdx.y * 128;
    int wr = wid >> 1, wc = wid & 1;
    int srow = tid >> 2;
    int scol = (tid & 3) * 8;
    f32x4 acc[4][4] = {};

    for (int kb = 0; kb < IN_DIM; kb += 32) {
        #pragma unroll
        for (int half = 0; half < 2; ++half) {
            const __hip_bfloat16* ga = xb + (size_t)(m0 + half * 64 + srow) * IN_DIM + kb + scol;
            const __hip_bfloat16* gb = wb + (size_t)(n0 + half * 64 + srow) * IN_DIM + kb + scol;
            __builtin_amdgcn_global_load_lds((const GLOBAL_AS void*)ga,
                (LDS_AS void*)(As + half * 2048 + wid * 512), 16, 0, 0);
            __builtin_amdgcn_global_load_lds((const GLOBAL_AS void*)gb,
                (LDS_AS void*)(Bs + half * 2048 + wid * 512), 16, 0, 0);
        }
        __syncthreads();
        int seg = (lane >> 4) * 8;
        int rl = lane & 15;
        short8 a[4], b[4];
        #pragma unroll
        for (int m = 0; m < 4; ++m)
            a[m] = *(const short8*)(As + (wr * 64 + m * 16 + rl) * 32 + seg);
        #pragma unroll
        for (int n = 0; n < 4; ++n)
            b[n] = *(const short8*)(Bs + (wc * 64 + n * 16 + rl) * 32 + seg);
        #pragma unroll
        for (int m = 0; m < 4; ++m)
            #pragma unroll
            for (int n = 0; n < 4; ++n)
                acc[m][n] = __builtin_amdgcn_mfma_f32_16x16x32_bf16(a[m], b[n], acc[m][n], 0, 0, 0);
        __syncthreads();
    }

    int kk = blockIdx.y >> 1;
    int col_l = lane & 15;
    int rseg = (lane >> 4) * 4;
    #pragma unroll
    for (int m = 0; m < 4; ++m) {
        int rbase = m0 + wr * 64 + m * 16 + rseg;
        float4 q0 = *(const float4*)(xninfo + 2 * rbase);
        float4 q1 = *(const float4*)(xninfo + 2 * rbase + 4);
        float nrm[4] = { q0.x, q0.z, q1.x, q1.z };
        float inv[4] = { q0.y, q0.w, q1.y, q1.w };
        #pragma unroll
        for (int n = 0; n < 4; ++n) {
            int col = n0 + wc * 64 + n * 16 + col_l;
            int h = col & 255;
            #pragma unroll
            for (int j = 0; j < 4; ++j) {
                float bv = nrm[j] * __expf(0.4f * acc[m][n][j] * inv[j] - 0.4f);
                bmat[((size_t)(rbase + j) * K_DIM + kk) * H_DIM + h] = __float2bfloat16(bv);
            }
        }
    }
}

// ---- Gram split-K partial: Mpart[kz] = wb2[:,kz*160:(kz+1)*160] @ wb2^T (128x128 tile) ----
__global__ __launch_bounds__(256) void gram_partial(const __hip_bfloat16* __restrict__ wb2,
        float* __restrict__ Mpart) {
    __shared__ __hip_bfloat16 As[4096];   // [128][32]
    __shared__ __hip_bfloat16 Bs[4096];
    int tid = threadIdx.x;
    int wid = tid >> 6, lane = tid & 63;
    int m0 = blockIdx.x * 128, n0 = blockIdx.y * 128;
    int kz = blockIdx.z;                  // 0..15, chunk of 160 = 5 steps of 32
    int wr = wid >> 1, wc = wid & 1;
    int srow = tid >> 2;
    int scol = (tid & 3) * 8;
    f32x4 acc[4][4] = {};

    for (int ks = 0; ks < 5; ++ks) {
        int kb = kz * 160 + ks * 32;
        #pragma unroll
        for (int half = 0; half < 2; ++half) {
            const __hip_bfloat16* ga = wb2 + (size_t)(m0 + half * 64 + srow) * NKH + kb + scol;
            const __hip_bfloat16* gb = wb2 + (size_t)(n0 + half * 64 + srow) * NKH + kb + scol;
            __builtin_amdgcn_global_load_lds((const GLOBAL_AS void*)ga,
                (LDS_AS void*)(As + half * 2048 + wid * 512), 16, 0, 0);
            __builtin_amdgcn_global_load_lds((const GLOBAL_AS void*)gb,
                (LDS_AS void*)(Bs + half * 2048 + wid * 512), 16, 0, 0);
        }
        __syncthreads();
        int seg = (lane >> 4) * 8;
        int rl = lane & 15;
        short8 a[4], b[4];
        #pragma unroll
        for (int m = 0; m < 4; ++m)
            a[m] = *(const short8*)(As + (wr * 64 + m * 16 + rl) * 32 + seg);
        #pragma unroll
        for (int n = 0; n < 4; ++n)
            b[n] = *(const short8*)(Bs + (wc * 64 + n * 16 + rl) * 32 + seg);
        #pragma unroll
        for (int m = 0; m < 4; ++m)
            #pragma unroll
            for (int n = 0; n < 4; ++n)
                acc[m][n] = __builtin_amdgcn_mfma_f32_16x16x32_bf16(a[m], b[n], acc[m][n], 0, 0, 0);
        __syncthreads();
    }

    float* dst = Mpart + (size_t)kz * 65536;
    int col_l = lane & 15;
    int rseg = (lane >> 4) * 4;
    #pragma unroll
    for (int m = 0; m < 4; ++m) {
        int rbase = m0 + wr * 64 + m * 16 + rseg;
        #pragma unroll
        for (int n = 0; n < 4; ++n) {
            int col = n0 + wc * 64 + n * 16 + col_l;
            #pragma unroll
            for (int j = 0; j < 4; ++j)
                dst[(size_t)(rbase + j) * H_DIM + col] = acc[m][n][j];
        }
    }
}

// ---- Gram finish: Mm = exp(0.4*sum_kz Mpart - 4), rsum[row] = row sum ----
__global__ __launch_bounds__(256) void gram_finish(const float* __restrict__ Mpart,
        float* __restrict__ Mm, float* __restrict__ rsum) {
    __shared__ float red[256];
    int r = blockIdx.x, c = threadIdx.x;
    float s = 0.f;
    #pragma unroll
    for (int kz = 0; kz < 16; ++kz)
        s += Mpart[(size_t)kz * 65536 + (size_t)r * H_DIM + c];
    float e = __expf(0.4f * s - 4.0f);
    Mm[(size_t)r * H_DIM + c] = e;
    red[c] = e;
    __syncthreads();
    #pragma unroll
    for (int st = 128; st > 0; st >>= 1) {
        if (c < st) red[c] += red[c + st];
        __syncthreads();
    }
    if (c == 0) rsum[r] = red[0];
}

// ---- shared power-iteration phase: fills vv (unit Perron vector), returns lam ----
__device__ __forceinline__ float power_phase(const float* __restrict__ Mm,
        const float* __restrict__ rsum, float* vv, float* red, int tid) {
    vv[tid] = rsum[tid];
    __syncthreads();
    float lam = 0.f;
    for (int it = 0; it <= NPOW; ++it) {
        float p = 0.f;
        #pragma unroll 8
        for (int g = 0; g < 256; ++g) p = fmaf(Mm[(size_t)g * 256 + tid], vv[g], p);
        __syncthreads();
        if (it < NPOW) {
            red[tid] = p * p;
            __syncthreads();
            #pragma unroll
            for (int st = 128; st > 0; st >>= 1) {
                if (tid < st) red[tid] += red[tid + st];
                __syncthreads();
            }
            float inv = rsqrtf(red[0]);
            __syncthreads();
            vv[tid] = p * inv;
            __syncthreads();
        } else {
            red[tid] = p * vv[tid];     // Rayleigh quotient (||v||=1)
            __syncthreads();
            #pragma unroll
            for (int st = 128; st > 0; st >>= 1) {
                if (tid < st) red[tid] += red[tid + st];
                __syncthreads();
            }
            lam = red[0];
            __syncthreads();
        }
    }
    return lam;
}

// ---- P2: E2 = E @ E, 16 blocks x 64x64 tile; embedded power phase; E from Mm on the fly ----
__global__ __launch_bounds__(256) void e2_kernel(const float* __restrict__ Mm,
        const float* __restrict__ rsum, float* __restrict__ E2g,
        __hip_bfloat16* __restrict__ e2b) {
    __shared__ __hip_bfloat16 EA[16384];   // [64][256] bf16, row-swizzled
    __shared__ __hip_bfloat16 EC[16384];
    __shared__ float vv[256];
    __shared__ float redl[256];
    int tid = threadIdx.x;
    int r0 = (blockIdx.x >> 2) * 64, c0 = (blockIdx.x & 3) * 64;
    float lam = power_phase(Mm, rsum, vv, redl, tid);
    float lm1 = lam - 1.f;
    char* pa = (char*)EA;
    char* pc = (char*)EC;
    for (int f = tid; f < 4096; f += 256) {
        int row = f >> 6, c4 = (f & 63) << 2;
        {
            int r = r0 + row;
            float4 mv = *(const float4*)(Mm + (size_t)r * 256 + c4);
            float vr = lm1 * vv[r];
            __hip_bfloat16 hb[4];
            hb[0] = __float2bfloat16(mv.x - ((r == c4 + 0) ? 1.f : 0.f) - vr * vv[c4 + 0]);
            hb[1] = __float2bfloat16(mv.y - ((r == c4 + 1) ? 1.f : 0.f) - vr * vv[c4 + 1]);
            hb[2] = __float2bfloat16(mv.z - ((r == c4 + 2) ? 1.f : 0.f) - vr * vv[c4 + 2]);
            hb[3] = __float2bfloat16(mv.w - ((r == c4 + 3) ? 1.f : 0.f) - vr * vv[c4 + 3]);
            *(short4*)(pa + row * 512 + ((c4 * 2) ^ ((row & 7) << 4))) = *(short4*)hb;
        }
        {
            int r = c0 + row;
            float4 mv = *(const float4*)(Mm + (size_t)r * 256 + c4);
            float vr = lm1 * vv[r];
            __hip_bfloat16 hb[4];
            hb[0] = __float2bfloat16(mv.x - ((r == c4 + 0) ? 1.f : 0.f) - vr * vv[c4 + 0]);
            hb[1] = __float2bfloat16(mv.y - ((r == c4 + 1) ? 1.f : 0.f) - vr * vv[c4 + 1]);
            hb[2] = __float2bfloat16(mv.z - ((r == c4 + 2) ? 1.f : 0.f) - vr * vv[c4 + 2]);
            hb[3] = __float2bfloat16(mv.w - ((r == c4 + 3) ? 1.f : 0.f) - vr * vv[c4 + 3]);
            *(short4*)(pc + row * 512 + ((c4 * 2) ^ ((row & 7) << 4))) = *(short4*)hb;
        }
    }
    __syncthreads();
    int wv = tid >> 6, lane = tid & 63;
    int rl = lane & 15, seg8 = (lane >> 4) * 8;
    f32x4 acc[4] = {};
    for (int kb = 0; kb < 256; kb += 32) {
        int row = wv * 16 + rl;
        short8 a = *(const short8*)(pa + row * 512 + (((kb + seg8) * 2) ^ ((rl & 7) << 4)));
        short8 b[4];
        #pragma unroll
        for (int n = 0; n < 4; ++n) {
            int rowb = n * 16 + rl;
            b[n] = *(const short8*)(pc + rowb * 512 + (((kb + seg8) * 2) ^ ((rl & 7) << 4)));
        }
        #pragma unroll
        for (int n = 0; n < 4; ++n)
            acc[n] = __builtin_amdgcn_mfma_f32_16x16x32_bf16(a, b[n], acc[n], 0, 0, 0);
    }
    int col_l = lane & 15, rseg = (lane >> 4) * 4;
    #pragma unroll
    for (int n = 0; n < 4; ++n) {
        #pragma unroll
        for (int j = 0; j < 4; ++j) {
            int r = r0 + wv * 16 + rseg + j;
            int c = c0 + n * 16 + col_l;
            size_t idx = (size_t)r * 256 + c;
            E2g[idx] = acc[n][j];
            e2b[idx] = __float2bfloat16(acc[n][j]);
        }
    }
}

// ---- P3: E3 = E @ E2; embedded power; lin = 1.5I - Mm/2 + (lm1/2+lfac) vv^T + 3/8 E2 - 5/16 E3
__global__ __launch_bounds__(256) void e3lin_kernel(const float* __restrict__ Mm,
        const float* __restrict__ rsum, const float* __restrict__ E2g,
        const __hip_bfloat16* __restrict__ e2b,
        float* __restrict__ lin, __hip_bfloat16* __restrict__ linb) {
    __shared__ __hip_bfloat16 EA[16384];   // [64][256] E rows, swizzled
    __shared__ __hip_bfloat16 EC[16384];   // [64][256] E2 rows (symmetric), swizzled
    __shared__ float vv[256];
    __shared__ float redl[256];
    int tid = threadIdx.x;
    int r0 = (blockIdx.x >> 2) * 64, c0 = (blockIdx.x & 3) * 64;
    float lam = power_phase(Mm, rsum, vv, redl, tid);
    float lm1 = lam - 1.f;
    float wfac = 0.5f * lm1 + (rsqrtf(lam) - 1.f);
    char* pa = (char*)EA;
    char* pc = (char*)EC;
    for (int f = tid; f < 4096; f += 256) {
        int row = f >> 6, c4 = (f & 63) << 2;
        int r = r0 + row;
        float4 mv = *(const float4*)(Mm + (size_t)r * 256 + c4);
        float vr = lm1 * vv[r];
        __hip_bfloat16 hb[4];
        hb[0] = __float2bfloat16(mv.x - ((r == c4 + 0) ? 1.f : 0.f) - vr * vv[c4 + 0]);
        hb[1] = __float2bfloat16(mv.y - ((r == c4 + 1) ? 1.f : 0.f) - vr * vv[c4 + 1]);
        hb[2] = __float2bfloat16(mv.z - ((r == c4 + 2) ? 1.f : 0.f) - vr * vv[c4 + 2]);
        hb[3] = __float2bfloat16(mv.w - ((r == c4 + 3) ? 1.f : 0.f) - vr * vv[c4 + 3]);
        *(short4*)(pa + row * 512 + ((c4 * 2) ^ ((row & 7) << 4))) = *(short4*)hb;
    }
    for (int f = tid; f < 2048; f += 256) {
        int row = f >> 5, c8 = (f & 31) << 3;
        short8 v8 = *(const short8*)(e2b + (size_t)(c0 + row) * 256 + c8);
        *(short8*)(pc + row * 512 + ((c8 * 2) ^ ((row & 7) << 4))) = v8;
    }
    __syncthreads();
    int wv = tid >> 6, lane = tid & 63;
    int rl = lane & 15, seg8 = (lane >> 4) * 8;
    f32x4 acc[4] = {};
    for (int kb = 0; kb < 256; kb += 32) {
        int row = wv * 16 + rl;
        short8 a = *(const short8*)(pa + row * 512 + (((kb + seg8) * 2) ^ ((rl & 7) << 4)));
        short8 b[4];
        #pragma unroll
        for (int n = 0; n < 4; ++n) {
            int rowb = n * 16 + rl;
            b[n] = *(const short8*)(pc + rowb * 512 + (((kb + seg8) * 2) ^ ((rl & 7) << 4)));
        }
        #pragma unroll
        for (int n = 0; n < 4; ++n)
            acc[n] = __builtin_amdgcn_mfma_f32_16x16x32_bf16(a, b[n], acc[n], 0, 0, 0);
    }
    int col_l = lane & 15, rseg = (lane >> 4) * 4;
    #pragma unroll
    for (int n = 0; n < 4; ++n) {
        #pragma unroll
        for (int j = 0; j < 4; ++j) {
            int r = r0 + wv * 16 + rseg + j;
            int c = c0 + n * 16 + col_l;
            size_t idx = (size_t)r * 256 + c;
            float lv = ((r == c) ? 1.5f : 0.f) - 0.5f * Mm[idx] + wfac * vv[r] * vv[c]
                     + 0.375f * E2g[idx] - 0.3125f * acc[n][j];
            lin[idx] = lv;
            linb[idx] = __float2bfloat16(lv);
        }
    }
}

// ---- megarec: recurrence (warm-up 32) + fused out1 = c9 @ linb per block ----
__global__ __launch_bounds__(256) void megarec(const __hip_bfloat16* __restrict__ bmat,
        const __hip_bfloat16* __restrict__ linb, float* __restrict__ out1,
        float* __restrict__ part, float* __restrict__ hxT) {
    __shared__ __hip_bfloat16 c9t[16384];  // [64][256] bf16, row-swizzled (32 KB)
    int tid = threadIdx.x;
    int s = blockIdx.x >> 5;
    int b = blockIdx.x & 31;
    int h = tid;
    int tout0 = s * 64;
    int t0 = (s == 0) ? 0 : tout0 - 32;
    int t1 = tout0 + 64;
    char* c9p = (char*)c9t;
    float c[10] = {};
    float s9 = 0.f;
    float bt[10];
    {
        const __hip_bfloat16* bp = bmat + ((size_t)(t0 * B_DIM + b) * K_DIM) * H_DIM + h;
        #pragma unroll
        for (int k = 0; k < 10; ++k) bt[k] = __bfloat162float(bp[k * H_DIM]);
    }
    for (int t = t0; t < t1; ++t) {
        int tn = (t + 1 < t1) ? t + 1 : t;
        float btn[10];
        const __hip_bfloat16* bq = bmat + ((size_t)(tn * B_DIM + b) * K_DIM) * H_DIM + h;
        #pragma unroll
        for (int k = 0; k < 10; ++k) btn[k] = __bfloat162float(bq[k * H_DIM]);
        #pragma unroll
        for (int j = 9; j >= 1; --j) c[j] = 0.5f * c[j] + c[j - 1] * bt[j];
        c[0] = 0.5f * c[0] + bt[0];
        if (t >= tout0) {
            int tt = t - tout0;
            *(__hip_bfloat16*)(c9p + tt * 512 + ((h * 2) ^ ((tt & 7) << 4))) = __float2bfloat16(c[9]);
            s9 += c[9];
        }
        #pragma unroll
        for (int k = 0; k < 10; ++k) bt[k] = btn[k];
    }
    part[(size_t)(s * B_DIM + b) * H_DIM + h] = s9;
    if (s == 7) {
        float* hp = hxT + (size_t)(b * H_DIM + h) * K_DIM;
        #pragma unroll
        for (int k = 0; k < 10; ++k) hp[k] = c[k];
    }
    __syncthreads();
    // out1 GEMM: [64 tt] x [256 h] @ linb -> out1[tout0+tt][b][g]; wave wid owns g in [wid*64,+64)
    int wid = tid >> 6, lane = tid & 63;
    int rl = lane & 15, seg8 = (lane >> 4) * 8;
    int col_l = lane & 15, rseg = (lane >> 4) * 4;
    f32x4 acc[4][4] = {};
    for (int kb = 0; kb < 256; kb += 32) {
        short8 a[4];
        #pragma unroll
        for (int m = 0; m < 4; ++m) {
            int row = m * 16 + rl;
            a[m] = *(const short8*)(c9p + row * 512 + (((kb + seg8) * 2) ^ ((row & 7) << 4)));
        }
        short8 bf[4];
        #pragma unroll
        for (int n = 0; n < 4; ++n)
            bf[n] = *(const short8*)(linb + (size_t)(wid * 64 + n * 16 + rl) * 256 + kb + seg8);
        #pragma unroll
        for (int m = 0; m < 4; ++m)
            #pragma unroll
            for (int n = 0; n < 4; ++n)
                acc[m][n] = __builtin_amdgcn_mfma_f32_16x16x32_bf16(a[m], bf[n], acc[m][n], 0, 0, 0);
    }
    #pragma unroll
    for (int m = 0; m < 4; ++m) {
        #pragma unroll
        for (int n = 0; n < 4; ++n) {
            int g = wid * 64 + n * 16 + col_l;
            #pragma unroll
            for (int j = 0; j < 4; ++j) {
                int tt = m * 16 + rseg + j;
                out1[((size_t)(tout0 + tt) * B_DIM + b) * H_DIM + g] = acc[m][n][j];
            }
        }
    }
}

// ---- recout: mean over T of c9 (from part) then out0 = mean @ lin, one block per b ----
__global__ __launch_bounds__(256) void recout_kernel(const float* __restrict__ part,
        const float* __restrict__ lin, float* __restrict__ out0) {
    __shared__ float mrow[256];
    int b = blockIdx.x, tid = threadIdx.x;
    float s = 0.f;
    #pragma unroll
    for (int j = 0; j < 8; ++j) s += part[(size_t)(j * B_DIM + b) * H_DIM + tid];
    mrow[tid] = s * (1.f / T_DIM);
    __syncthreads();
    float acc = 0.f;
    #pragma unroll 8
    for (int h = 0; h < H_DIM; ++h) acc = fmaf(mrow[h], lin[(size_t)h * H_DIM + tid], acc);
    out0[b * H_DIM + tid] = acc;
}

extern "C" void kernel_launch(void* const* d_in, const int* in_sizes, int n_in,
                              void* d_out, int out_size, void* d_ws, size_t ws_size,
                              hipStream_t stream) {
    const float* x = (const float*)d_in[0];
    const float* w = (const float*)d_in[1];
    float* out0 = (float*)d_out;                       // B*H
    float* out1 = out0 + (size_t)B_DIM * H_DIM;        // T*B*H
    float* hxT  = out1 + (size_t)TB * H_DIM;           // B*H*K

    char* ws = (char*)d_ws;
    __hip_bfloat16* wb   = (__hip_bfloat16*)(ws + 0);          // 1,310,720
    __hip_bfloat16* wb2  = (__hip_bfloat16*)(ws + 1310720);    // 1,310,720
    float* xninfo        = (float*)(ws + 2621440);             //   131,072
    float* Mm            = (float*)(ws + 2752512);             //   262,144
    float* rsum          = (float*)(ws + 3014656);             //     1,024
    float* E2g           = (float*)(ws + 3015680);             //   262,144
    __hip_bfloat16* e2b  = (__hip_bfloat16*)(ws + 3277824);    //   131,072
    float* lin           = (float*)(ws + 3408896);             //   262,144
    __hip_bfloat16* linb = (__hip_bfloat16*)(ws + 3671040);    //   131,072
    float* part          = (float*)(ws + 3802112);             //   262,144
    float* Mpart         = (float*)(ws + 4064256);             // 4,194,304
    __hip_bfloat16* xb   = (__hip_bfloat16*)(ws + 8258560);    // 8,388,608
    __hip_bfloat16* bmat = (__hip_bfloat16*)(ws + 16647168);   // 83,886,080 -> ~100.5 MB

    prep_kernel<<<dim3(4736), dim3(256), 0, stream>>>(w, x, wb, wb2, xninfo, xb);
    gemm_b_mfma<<<dim3(128, 20), dim3(256), 0, stream>>>(xb, wb, xninfo, bmat);
    gram_partial<<<dim3(2, 2, 16), dim3(256), 0, stream>>>(wb2, Mpart);
    gram_finish<<<dim3(256), dim3(256), 0, stream>>>(Mpart, Mm, rsum);
    e2_kernel<<<dim3(16), dim3(256), 0, stream>>>(Mm, rsum, E2g, e2b);
    e3lin_kernel<<<dim3(16), dim3(256), 0, stream>>>(Mm, rsum, E2g, e2b, lin, linb);
    megarec<<<dim3(256), dim3(256), 0, stream>>>(bmat, linb, out1, part, hxT);
    recout_kernel<<<dim3(32), dim3(256), 0, stream>>>(part, lin, out0);
}

// Round 9
// 164.502 us; speedup vs baseline: 1.0562x; 1.0562x over previous
//
#include <hip/hip_runtime.h>
#include <hip/hip_bf16.h>

// Problem dims
#define T_DIM 512
#define B_DIM 32
#define IN_DIM 256
#define H_DIM 256
#define K_DIM 10
#define TB 16384          // T*B
#define NKH 2560          // H*K
#define NPOW 3            // normalized power updates (v0 = rsum = M@1 is already 1 step)

typedef __attribute__((ext_vector_type(8))) short short8;
typedef __attribute__((ext_vector_type(4))) float f32x4;
typedef __attribute__((ext_vector_type(4), aligned(4))) int int4u;   // 4B-aligned dwordx4

#define GLOBAL_AS __attribute__((address_space(1)))
#define LDS_AS __attribute__((address_space(3)))

__device__ __forceinline__ float wave_sum64(float v) {
    #pragma unroll
    for (int off = 32; off > 0; off >>= 1) v += __shfl_xor(v, off, 64);
    return v;
}

__device__ __forceinline__ float bf_lo(int u) { return __int_as_float(u << 16); }
__device__ __forceinline__ float bf_hi(int u) { return __int_as_float(u & 0xffff0000); }

// ---- prep: weight normalize (blocks 0..639) + x norms/bf16 (blocks 640..4735) ----
// wb bf16 [h*10+k][256] (ORIGINAL row order, for gemm_b); wb2 bf16 [h][k*256+i] (for gram)
__global__ __launch_bounds__(256) void prep_kernel(const float* __restrict__ w,
        const float* __restrict__ x, __hip_bfloat16* __restrict__ wb,
        __hip_bfloat16* __restrict__ wb2, float* __restrict__ xninfo,
        __hip_bfloat16* __restrict__ xb) {
    int wv = threadIdx.x >> 6, lane = threadIdx.x & 63;
    if (blockIdx.x < 640) {
        int row = blockIdx.x * 4 + wv;                 // 0..2559  (= h*10+k)
        const float* src = w + (size_t)row * IN_DIM;
        float v[4]; float s = 0.f;
        #pragma unroll
        for (int j = 0; j < 4; ++j) { v[j] = src[lane + 64 * j]; s += v[j] * v[j]; }
        s = wave_sum64(s);
        float inv = 1.f / fmaxf(sqrtf(s), 1e-4f);
        int h = row / K_DIM, k = row % K_DIM;
        __hip_bfloat16* d1 = wb + (size_t)row * IN_DIM;
        __hip_bfloat16* d2 = wb2 + (size_t)h * NKH + k * IN_DIM;
        #pragma unroll
        for (int j = 0; j < 4; ++j) {
            __hip_bfloat16 t = __float2bfloat16(v[j] * inv);
            d1[lane + 64 * j] = t;
            d2[lane + 64 * j] = t;
        }
    } else {
        int row = (blockIdx.x - 640) * 4 + wv;         // 0..16383
        const float* src = x + (size_t)row * IN_DIM;
        float v[4]; float s = 0.f;
        #pragma unroll
        for (int j = 0; j < 4; ++j) { v[j] = src[lane + 64 * j]; s += v[j] * v[j]; }
        s = wave_sum64(s);
        float nrm = sqrtf(s);
        if (lane == 0) { xninfo[2 * row] = nrm; xninfo[2 * row + 1] = 1.f / fmaxf(nrm, 1e-4f); }
        __hip_bfloat16* d = xb + (size_t)row * IN_DIM;
        #pragma unroll
        for (int j = 0; j < 4; ++j) d[lane + 64 * j] = __float2bfloat16(v[j]);
    }
}

// ---- big GEMM via bf16 MFMA + kappa epilogue -> bmat bf16 [t][b][h*10+k] ----
__global__ __launch_bounds__(256) void gemm_b_mfma(const __hip_bfloat16* __restrict__ xb,
        const __hip_bfloat16* __restrict__ wb, const float* __restrict__ xninfo,
        __hip_bfloat16* __restrict__ bmat) {
    __shared__ __hip_bfloat16 As[4096];   // [128][32]
    __shared__ __hip_bfloat16 Bs[4096];
    int tid = threadIdx.x;
    int wid = tid >> 6, lane = tid & 63;
    int m0 = blockIdx.x * 128, n0 = blockIdx.y * 128;
    int wr = wid >> 1, wc = wid & 1;
    int srow = tid >> 2;
    int scol = (tid & 3) * 8;
    f32x4 acc[4][4] = {};

    for (int kb = 0; kb < IN_DIM; kb += 32) {
        #pragma unroll
        for (int half = 0; half < 2; ++half) {
            const __hip_bfloat16* ga = xb + (size_t)(m0 + half * 64 + srow) * IN_DIM + kb + scol;
            const __hip_bfloat16* gb = wb + (size_t)(n0 + half * 64 + srow) * IN_DIM + kb + scol;
            __builtin_amdgcn_global_load_lds((const GLOBAL_AS void*)ga,
                (LDS_AS void*)(As + half * 2048 + wid * 512), 16, 0, 0);
            __builtin_amdgcn_global_load_lds((const GLOBAL_AS void*)gb,
                (LDS_AS void*)(Bs + half * 2048 + wid * 512), 16, 0, 0);
        }
        __syncthreads();
        int seg = (lane >> 4) * 8;
        int rl = lane & 15;
        short8 a[4], b[4];
        #pragma unroll
        for (int m = 0; m < 4; ++m)
            a[m] = *(const short8*)(As + (wr * 64 + m * 16 + rl) * 32 + seg);
        #pragma unroll
        for (int n = 0; n < 4; ++n)
            b[n] = *(const short8*)(Bs + (wc * 64 + n * 16 + rl) * 32 + seg);
        #pragma unroll
        for (int m = 0; m < 4; ++m)
            #pragma unroll
            for (int n = 0; n < 4; ++n)
                acc[m][n] = __builtin_amdgcn_mfma_f32_16x16x32_bf16(a[m], b[n], acc[m][n], 0, 0, 0);
        __syncthreads();
    }

    int col_l = lane & 15;
    int rseg = (lane >> 4) * 4;
    #pragma unroll
    for (int m = 0; m < 4; ++m) {
        int rbase = m0 + wr * 64 + m * 16 + rseg;
        float4 q0 = *(const float4*)(xninfo + 2 * rbase);
        float4 q1 = *(const float4*)(xninfo + 2 * rbase + 4);
        float nrm[4] = { q0.x, q0.z, q1.x, q1.z };
        float inv[4] = { q0.y, q0.w, q1.y, q1.w };
        #pragma unroll
        for (int n = 0; n < 4; ++n) {
            int col = n0 + wc * 64 + n * 16 + col_l;     // = h*10+k directly
            #pragma unroll
            for (int j = 0; j < 4; ++j) {
                float bv = nrm[j] * __expf(0.4f * acc[m][n][j] * inv[j] - 0.4f);
                bmat[(size_t)(rbase + j) * NKH + col] = __float2bfloat16(bv);
            }
        }
    }
}

// ---- Gram split-K partial: Mpart[kz] = wb2[:,kz*160:(kz+1)*160] @ wb2^T (128x128 tile) ----
__global__ __launch_bounds__(256) void gram_partial(const __hip_bfloat16* __restrict__ wb2,
        float* __restrict__ Mpart) {
    __shared__ __hip_bfloat16 As[4096];   // [128][32]
    __shared__ __hip_bfloat16 Bs[4096];
    int tid = threadIdx.x;
    int wid = tid >> 6, lane = tid & 63;
    int m0 = blockIdx.x * 128, n0 = blockIdx.y * 128;
    int kz = blockIdx.z;                  // 0..15, chunk of 160 = 5 steps of 32
    int wr = wid >> 1, wc = wid & 1;
    int srow = tid >> 2;
    int scol = (tid & 3) * 8;
    f32x4 acc[4][4] = {};

    for (int ks = 0; ks < 5; ++ks) {
        int kb = kz * 160 + ks * 32;
        #pragma unroll
        for (int half = 0; half < 2; ++half) {
            const __hip_bfloat16* ga = wb2 + (size_t)(m0 + half * 64 + srow) * NKH + kb + scol;
            const __hip_bfloat16* gb = wb2 + (size_t)(n0 + half * 64 + srow) * NKH + kb + scol;
            __builtin_amdgcn_global_load_lds((const GLOBAL_AS void*)ga,
                (LDS_AS void*)(As + half * 2048 + wid * 512), 16, 0, 0);
            __builtin_amdgcn_global_load_lds((const GLOBAL_AS void*)gb,
                (LDS_AS void*)(Bs + half * 2048 + wid * 512), 16, 0, 0);
        }
        __syncthreads();
        int seg = (lane >> 4) * 8;
        int rl = lane & 15;
        short8 a[4], b[4];
        #pragma unroll
        for (int m = 0; m < 4; ++m)
            a[m] = *(const short8*)(As + (wr * 64 + m * 16 + rl) * 32 + seg);
        #pragma unroll
        for (int n = 0; n < 4; ++n)
            b[n] = *(const short8*)(Bs + (wc * 64 + n * 16 + rl) * 32 + seg);
        #pragma unroll
        for (int m = 0; m < 4; ++m)
            #pragma unroll
            for (int n = 0; n < 4; ++n)
                acc[m][n] = __builtin_amdgcn_mfma_f32_16x16x32_bf16(a[m], b[n], acc[m][n], 0, 0, 0);
        __syncthreads();
    }

    float* dst = Mpart + (size_t)kz * 65536;
    int col_l = lane & 15;
    int rseg = (lane >> 4) * 4;
    #pragma unroll
    for (int m = 0; m < 4; ++m) {
        int rbase = m0 + wr * 64 + m * 16 + rseg;
        #pragma unroll
        for (int n = 0; n < 4; ++n) {
            int col = n0 + wc * 64 + n * 16 + col_l;
            #pragma unroll
            for (int j = 0; j < 4; ++j)
                dst[(size_t)(rbase + j) * H_DIM + col] = acc[m][n][j];
        }
    }
}

// ---- Gram finish: Mm = exp(0.4*sum_kz Mpart - 4), rsum[row] = row sum ----
__global__ __launch_bounds__(256) void gram_finish(const float* __restrict__ Mpart,
        float* __restrict__ Mm, float* __restrict__ rsum) {
    __shared__ float red[256];
    int r = blockIdx.x, c = threadIdx.x;
    float s = 0.f;
    #pragma unroll
    for (int kz = 0; kz < 16; ++kz)
        s += Mpart[(size_t)kz * 65536 + (size_t)r * H_DIM + c];
    float e = __expf(0.4f * s - 4.0f);
    Mm[(size_t)r * H_DIM + c] = e;
    red[c] = e;
    __syncthreads();
    #pragma unroll
    for (int st = 128; st > 0; st >>= 1) {
        if (c < st) red[c] += red[c + st];
        __syncthreads();
    }
    if (c == 0) rsum[r] = red[0];
}

// ---- shared power-iteration phase: fills vv (unit Perron vector), returns lam ----
__device__ __forceinline__ float power_phase(const float* __restrict__ Mm,
        const float* __restrict__ rsum, float* vv, float* red, int tid) {
    vv[tid] = rsum[tid];
    __syncthreads();
    float lam = 0.f;
    for (int it = 0; it <= NPOW; ++it) {
        float p = 0.f;
        #pragma unroll 8
        for (int g = 0; g < 256; ++g) p = fmaf(Mm[(size_t)g * 256 + tid], vv[g], p);
        __syncthreads();
        if (it < NPOW) {
            red[tid] = p * p;
            __syncthreads();
            #pragma unroll
            for (int st = 128; st > 0; st >>= 1) {
                if (tid < st) red[tid] += red[tid + st];
                __syncthreads();
            }
            float inv = rsqrtf(red[0]);
            __syncthreads();
            vv[tid] = p * inv;
            __syncthreads();
        } else {
            red[tid] = p * vv[tid];     // Rayleigh quotient (||v||=1)
            __syncthreads();
            #pragma unroll
            for (int st = 128; st > 0; st >>= 1) {
                if (tid < st) red[tid] += red[tid + st];
                __syncthreads();
            }
            lam = red[0];
            __syncthreads();
        }
    }
    return lam;
}

// ---- P2: E2 = E @ E, 16 blocks x 64x64 tile; embedded power phase; E from Mm on the fly ----
__global__ __launch_bounds__(256) void e2_kernel(const float* __restrict__ Mm,
        const float* __restrict__ rsum, float* __restrict__ E2g,
        __hip_bfloat16* __restrict__ e2b) {
    __shared__ __hip_bfloat16 EA[16384];   // [64][256] bf16, row-swizzled
    __shared__ __hip_bfloat16 EC[16384];
    __shared__ float vv[256];
    __shared__ float redl[256];
    int tid = threadIdx.x;
    int r0 = (blockIdx.x >> 2) * 64, c0 = (blockIdx.x & 3) * 64;
    float lam = power_phase(Mm, rsum, vv, redl, tid);
    float lm1 = lam - 1.f;
    char* pa = (char*)EA;
    char* pc = (char*)EC;
    for (int f = tid; f < 4096; f += 256) {
        int row = f >> 6, c4 = (f & 63) << 2;
        {
            int r = r0 + row;
            float4 mv = *(const float4*)(Mm + (size_t)r * 256 + c4);
            float vr = lm1 * vv[r];
            __hip_bfloat16 hb[4];
            hb[0] = __float2bfloat16(mv.x - ((r == c4 + 0) ? 1.f : 0.f) - vr * vv[c4 + 0]);
            hb[1] = __float2bfloat16(mv.y - ((r == c4 + 1) ? 1.f : 0.f) - vr * vv[c4 + 1]);
            hb[2] = __float2bfloat16(mv.z - ((r == c4 + 2) ? 1.f : 0.f) - vr * vv[c4 + 2]);
            hb[3] = __float2bfloat16(mv.w - ((r == c4 + 3) ? 1.f : 0.f) - vr * vv[c4 + 3]);
            *(short4*)(pa + row * 512 + ((c4 * 2) ^ ((row & 7) << 4))) = *(short4*)hb;
        }
        {
            int r = c0 + row;
            float4 mv = *(const float4*)(Mm + (size_t)r * 256 + c4);
            float vr = lm1 * vv[r];
            __hip_bfloat16 hb[4];
            hb[0] = __float2bfloat16(mv.x - ((r == c4 + 0) ? 1.f : 0.f) - vr * vv[c4 + 0]);
            hb[1] = __float2bfloat16(mv.y - ((r == c4 + 1) ? 1.f : 0.f) - vr * vv[c4 + 1]);
            hb[2] = __float2bfloat16(mv.z - ((r == c4 + 2) ? 1.f : 0.f) - vr * vv[c4 + 2]);
            hb[3] = __float2bfloat16(mv.w - ((r == c4 + 3) ? 1.f : 0.f) - vr * vv[c4 + 3]);
            *(short4*)(pc + row * 512 + ((c4 * 2) ^ ((row & 7) << 4))) = *(short4*)hb;
        }
    }
    __syncthreads();
    int wv = tid >> 6, lane = tid & 63;
    int rl = lane & 15, seg8 = (lane >> 4) * 8;
    f32x4 acc[4] = {};
    for (int kb = 0; kb < 256; kb += 32) {
        int row = wv * 16 + rl;
        short8 a = *(const short8*)(pa + row * 512 + (((kb + seg8) * 2) ^ ((rl & 7) << 4)));
        short8 b[4];
        #pragma unroll
        for (int n = 0; n < 4; ++n) {
            int rowb = n * 16 + rl;
            b[n] = *(const short8*)(pc + rowb * 512 + (((kb + seg8) * 2) ^ ((rl & 7) << 4)));
        }
        #pragma unroll
        for (int n = 0; n < 4; ++n)
            acc[n] = __builtin_amdgcn_mfma_f32_16x16x32_bf16(a, b[n], acc[n], 0, 0, 0);
    }
    int col_l = lane & 15, rseg = (lane >> 4) * 4;
    #pragma unroll
    for (int n = 0; n < 4; ++n) {
        #pragma unroll
        for (int j = 0; j < 4; ++j) {
            int r = r0 + wv * 16 + rseg + j;
            int c = c0 + n * 16 + col_l;
            size_t idx = (size_t)r * 256 + c;
            E2g[idx] = acc[n][j];
            e2b[idx] = __float2bfloat16(acc[n][j]);
        }
    }
}

// ---- P3: E3 = E @ E2; embedded power; lin = 1.5I - Mm/2 + (lm1/2+lfac) vv^T + 3/8 E2 - 5/16 E3
__global__ __launch_bounds__(256) void e3lin_kernel(const float* __restrict__ Mm,
        const float* __restrict__ rsum, const float* __restrict__ E2g,
        const __hip_bfloat16* __restrict__ e2b,
        float* __restrict__ lin, __hip_bfloat16* __restrict__ linb) {
    __shared__ __hip_bfloat16 EA[16384];   // [64][256] E rows, swizzled
    __shared__ __hip_bfloat16 EC[16384];   // [64][256] E2 rows (symmetric), swizzled
    __shared__ float vv[256];
    __shared__ float redl[256];
    int tid = threadIdx.x;
    int r0 = (blockIdx.x >> 2) * 64, c0 = (blockIdx.x & 3) * 64;
    float lam = power_phase(Mm, rsum, vv, redl, tid);
    float lm1 = lam - 1.f;
    float wfac = 0.5f * lm1 + (rsqrtf(lam) - 1.f);
    char* pa = (char*)EA;
    char* pc = (char*)EC;
    for (int f = tid; f < 4096; f += 256) {
        int row = f >> 6, c4 = (f & 63) << 2;
        int r = r0 + row;
        float4 mv = *(const float4*)(Mm + (size_t)r * 256 + c4);
        float vr = lm1 * vv[r];
        __hip_bfloat16 hb[4];
        hb[0] = __float2bfloat16(mv.x - ((r == c4 + 0) ? 1.f : 0.f) - vr * vv[c4 + 0]);
        hb[1] = __float2bfloat16(mv.y - ((r == c4 + 1) ? 1.f : 0.f) - vr * vv[c4 + 1]);
        hb[2] = __float2bfloat16(mv.z - ((r == c4 + 2) ? 1.f : 0.f) - vr * vv[c4 + 2]);
        hb[3] = __float2bfloat16(mv.w - ((r == c4 + 3) ? 1.f : 0.f) - vr * vv[c4 + 3]);
        *(short4*)(pa + row * 512 + ((c4 * 2) ^ ((row & 7) << 4))) = *(short4*)hb;
    }
    for (int f = tid; f < 2048; f += 256) {
        int row = f >> 5, c8 = (f & 31) << 3;
        short8 v8 = *(const short8*)(e2b + (size_t)(c0 + row) * 256 + c8);
        *(short8*)(pc + row * 512 + ((c8 * 2) ^ ((row & 7) << 4))) = v8;
    }
    __syncthreads();
    int wv = tid >> 6, lane = tid & 63;
    int rl = lane & 15, seg8 = (lane >> 4) * 8;
    f32x4 acc[4] = {};
    for (int kb = 0; kb < 256; kb += 32) {
        int row = wv * 16 + rl;
        short8 a = *(const short8*)(pa + row * 512 + (((kb + seg8) * 2) ^ ((rl & 7) << 4)));
        short8 b[4];
        #pragma unroll
        for (int n = 0; n < 4; ++n) {
            int rowb = n * 16 + rl;
            b[n] = *(const short8*)(pc + rowb * 512 + (((kb + seg8) * 2) ^ ((rl & 7) << 4)));
        }
        #pragma unroll
        for (int n = 0; n < 4; ++n)
            acc[n] = __builtin_amdgcn_mfma_f32_16x16x32_bf16(a, b[n], acc[n], 0, 0, 0);
    }
    int col_l = lane & 15, rseg = (lane >> 4) * 4;
    #pragma unroll
    for (int n = 0; n < 4; ++n) {
        #pragma unroll
        for (int j = 0; j < 4; ++j) {
            int r = r0 + wv * 16 + rseg + j;
            int c = c0 + n * 16 + col_l;
            size_t idx = (size_t)r * 256 + c;
            float lv = ((r == c) ? 1.5f : 0.f) - 0.5f * Mm[idx] + wfac * vv[r] * vv[c]
                     + 0.375f * E2g[idx] - 0.3125f * acc[n][j];
            lin[idx] = lv;
            linb[idx] = __float2bfloat16(lv);
        }
    }
}

// ---- megarec: 16 chunks x 32 outputs (warm-up 32) + fused out1 = c9 @ linb ----
// bmat layout [t][b][h*10+k]: thread h reads 20 contiguous bytes per step (dwordx4 + dword).
__global__ __launch_bounds__(256) void megarec(const __hip_bfloat16* __restrict__ bmat,
        const __hip_bfloat16* __restrict__ linb, float* __restrict__ out1,
        float* __restrict__ part, float* __restrict__ hxT) {
    __shared__ __hip_bfloat16 c9t[8192];   // [32][256] bf16, row-swizzled (16 KB)
    int tid = threadIdx.x;
    int s = blockIdx.x >> 5;               // 0..15
    int b = blockIdx.x & 31;
    int h = tid;
    int tout0 = s * 32;
    int t0 = (s == 0) ? 0 : tout0 - 32;
    int t1 = tout0 + 32;
    char* c9p = (char*)c9t;
    float c[10] = {};
    float s9 = 0.f;
    int4u v0; int v1;
    {
        const char* bp = (const char*)bmat + ((size_t)(t0 * B_DIM + b) * NKH + h * 10) * 2;
        v0 = *(const int4u*)bp;
        v1 = *(const int*)(bp + 16);
    }
    for (int t = t0; t < t1; ++t) {
        int tn = (t + 1 < t1) ? t + 1 : t;
        const char* bq = (const char*)bmat + ((size_t)(tn * B_DIM + b) * NKH + h * 10) * 2;
        int4u w0 = *(const int4u*)bq;
        int w1 = *(const int*)(bq + 16);
        float bt[10];
        bt[0] = bf_lo(v0.x); bt[1] = bf_hi(v0.x);
        bt[2] = bf_lo(v0.y); bt[3] = bf_hi(v0.y);
        bt[4] = bf_lo(v0.z); bt[5] = bf_hi(v0.z);
        bt[6] = bf_lo(v0.w); bt[7] = bf_hi(v0.w);
        bt[8] = bf_lo(v1);   bt[9] = bf_hi(v1);
        #pragma unroll
        for (int j = 9; j >= 1; --j) c[j] = 0.5f * c[j] + c[j - 1] * bt[j];
        c[0] = 0.5f * c[0] + bt[0];
        if (t >= tout0) {
            int tt = t - tout0;
            *(__hip_bfloat16*)(c9p + tt * 512 + ((h * 2) ^ ((tt & 7) << 4))) = __float2bfloat16(c[9]);
            s9 += c[9];
        }
        v0 = w0; v1 = w1;
    }
    part[(size_t)(s * B_DIM + b) * H_DIM + h] = s9;
    if (s == 15) {
        float* hp = hxT + (size_t)(b * H_DIM + h) * K_DIM;
        #pragma unroll
        for (int k = 0; k < 10; ++k) hp[k] = c[k];
    }
    __syncthreads();
    // out1 GEMM: [32 tt] x [256 h] @ linb -> out1[tout0+tt][b][g]; wave wid owns g in [wid*64,+64)
    int wid = tid >> 6, lane = tid & 63;
    int rl = lane & 15, seg8 = (lane >> 4) * 8;
    int col_l = lane & 15, rseg = (lane >> 4) * 4;
    f32x4 acc[2][4] = {};
    for (int kb = 0; kb < 256; kb += 32) {
        short8 a[2];
        #pragma unroll
        for (int m = 0; m < 2; ++m) {
            int row = m * 16 + rl;
            a[m] = *(const short8*)(c9p + row * 512 + (((kb + seg8) * 2) ^ ((row & 7) << 4)));
        }
        short8 bf[4];
        #pragma unroll
        for (int n = 0; n < 4; ++n)
            bf[n] = *(const short8*)(linb + (size_t)(wid * 64 + n * 16 + rl) * 256 + kb + seg8);
        #pragma unroll
        for (int m = 0; m < 2; ++m)
            #pragma unroll
            for (int n = 0; n < 4; ++n)
                acc[m][n] = __builtin_amdgcn_mfma_f32_16x16x32_bf16(a[m], bf[n], acc[m][n], 0, 0, 0);
    }
    #pragma unroll
    for (int m = 0; m < 2; ++m) {
        #pragma unroll
        for (int n = 0; n < 4; ++n) {
            int g = wid * 64 + n * 16 + col_l;
            #pragma unroll
            for (int j = 0; j < 4; ++j) {
                int tt = m * 16 + rseg + j;
                out1[((size_t)(tout0 + tt) * B_DIM + b) * H_DIM + g] = acc[m][n][j];
            }
        }
    }
}

// ---- recout: mean over T of c9 (from part) then out0 = mean @ lin, one block per b ----
__global__ __launch_bounds__(256) void recout_kernel(const float* __restrict__ part,
        const float* __restrict__ lin, float* __restrict__ out0) {
    __shared__ float mrow[256];
    int b = blockIdx.x, tid = threadIdx.x;
    float s = 0.f;
    #pragma unroll
    for (int j = 0; j < 16; ++j) s += part[(size_t)(j * B_DIM + b) * H_DIM + tid];
    mrow[tid] = s * (1.f / T_DIM);
    __syncthreads();
    float acc = 0.f;
    #pragma unroll 8
    for (int h = 0; h < H_DIM; ++h) acc = fmaf(mrow[h], lin[(size_t)h * H_DIM + tid], acc);
    out0[b * H_DIM + tid] = acc;
}

extern "C" void kernel_launch(void* const* d_in, const int* in_sizes, int n_in,
                              void* d_out, int out_size, void* d_ws, size_t ws_size,
                              hipStream_t stream) {
    const float* x = (const float*)d_in[0];
    const float* w = (const float*)d_in[1];
    float* out0 = (float*)d_out;                       // B*H
    float* out1 = out0 + (size_t)B_DIM * H_DIM;        // T*B*H
    float* hxT  = out1 + (size_t)TB * H_DIM;           // B*H*K

    char* ws = (char*)d_ws;
    __hip_bfloat16* wb   = (__hip_bfloat16*)(ws + 0);          // 1,310,720
    __hip_bfloat16* wb2  = (__hip_bfloat16*)(ws + 1310720);    // 1,310,720
    float* xninfo        = (float*)(ws + 2621440);             //   131,072
    float* Mm            = (float*)(ws + 2752512);             //   262,144
    float* rsum          = (float*)(ws + 3014656);             //     1,024
    float* E2g           = (float*)(ws + 3015680);             //   262,144
    __hip_bfloat16* e2b  = (__hip_bfloat16*)(ws + 3277824);    //   131,072
    float* lin           = (float*)(ws + 3408896);             //   262,144
    __hip_bfloat16* linb = (__hip_bfloat16*)(ws + 3671040);    //   131,072
    float* part          = (float*)(ws + 3802112);             //   524,288 (16 chunks)
    float* Mpart         = (float*)(ws + 4326400);             // 4,194,304
    __hip_bfloat16* xb   = (__hip_bfloat16*)(ws + 8520704);    // 8,388,608
    __hip_bfloat16* bmat = (__hip_bfloat16*)(ws + 16909312);   // 83,886,080 -> ~100.8 MB

    prep_kernel<<<dim3(4736), dim3(256), 0, stream>>>(w, x, wb, wb2, xninfo, xb);
    gemm_b_mfma<<<dim3(128, 20), dim3(256), 0, stream>>>(xb, wb, xninfo, bmat);
    gram_partial<<<dim3(2, 2, 16), dim3(256), 0, stream>>>(wb2, Mpart);
    gram_finish<<<dim3(256), dim3(256), 0, stream>>>(Mpart, Mm, rsum);
    e2_kernel<<<dim3(16), dim3(256), 0, stream>>>(Mm, rsum, E2g, e2b);
    e3lin_kernel<<<dim3(16), dim3(256), 0, stream>>>(Mm, rsum, E2g, e2b, lin, linb);
    megarec<<<dim3(512), dim3(256), 0, stream>>>(bmat, linb, out1, part, hxT);
    recout_kernel<<<dim3(32), dim3(256), 0, stream>>>(part, lin, out0);
}

// Round 10
// 163.373 us; speedup vs baseline: 1.0635x; 1.0069x over previous
//
#include <hip/hip_runtime.h>
#include <hip/hip_bf16.h>

// Problem dims
#define T_DIM 512
#define B_DIM 32
#define IN_DIM 256
#define H_DIM 256
#define K_DIM 10
#define TB 16384          // T*B
#define NKH 2560          // H*K
#define NPOW 3            // normalized power updates (v0 = rsum = M@1 is already 1 step)

typedef __attribute__((ext_vector_type(8))) short short8;
typedef __attribute__((ext_vector_type(4))) float f32x4;
typedef __attribute__((ext_vector_type(4), aligned(4))) int int4u;   // 4B-aligned dwordx4

#define GLOBAL_AS __attribute__((address_space(1)))
#define LDS_AS __attribute__((address_space(3)))

__device__ __forceinline__ float wave_sum64(float v) {
    #pragma unroll
    for (int off = 32; off > 0; off >>= 1) v += __shfl_xor(v, off, 64);
    return v;
}

__device__ __forceinline__ float bf_lo(int u) { return __int_as_float(u << 16); }
__device__ __forceinline__ float bf_hi(int u) { return __int_as_float(u & 0xffff0000); }

// ---- prep: weight normalize (blocks 0..639) + x norms/bf16 (blocks 640..4735) ----
// wb bf16 [h*10+k][256] (ORIGINAL row order, for gemm_b); wb2 bf16 [h][k*256+i] (for gram)
__global__ __launch_bounds__(256) void prep_kernel(const float* __restrict__ w,
        const float* __restrict__ x, __hip_bfloat16* __restrict__ wb,
        __hip_bfloat16* __restrict__ wb2, float* __restrict__ xninfo,
        __hip_bfloat16* __restrict__ xb) {
    int wv = threadIdx.x >> 6, lane = threadIdx.x & 63;
    if (blockIdx.x < 640) {
        int row = blockIdx.x * 4 + wv;                 // 0..2559  (= h*10+k)
        const float* src = w + (size_t)row * IN_DIM;
        float v[4]; float s = 0.f;
        #pragma unroll
        for (int j = 0; j < 4; ++j) { v[j] = src[lane + 64 * j]; s += v[j] * v[j]; }
        s = wave_sum64(s);
        float inv = 1.f / fmaxf(sqrtf(s), 1e-4f);
        int h = row / K_DIM, k = row % K_DIM;
        __hip_bfloat16* d1 = wb + (size_t)row * IN_DIM;
        __hip_bfloat16* d2 = wb2 + (size_t)h * NKH + k * IN_DIM;
        #pragma unroll
        for (int j = 0; j < 4; ++j) {
            __hip_bfloat16 t = __float2bfloat16(v[j] * inv);
            d1[lane + 64 * j] = t;
            d2[lane + 64 * j] = t;
        }
    } else {
        int row = (blockIdx.x - 640) * 4 + wv;         // 0..16383
        const float* src = x + (size_t)row * IN_DIM;
        float v[4]; float s = 0.f;
        #pragma unroll
        for (int j = 0; j < 4; ++j) { v[j] = src[lane + 64 * j]; s += v[j] * v[j]; }
        s = wave_sum64(s);
        float nrm = sqrtf(s);
        if (lane == 0) { xninfo[2 * row] = nrm; xninfo[2 * row + 1] = 1.f / fmaxf(nrm, 1e-4f); }
        __hip_bfloat16* d = xb + (size_t)row * IN_DIM;
        #pragma unroll
        for (int j = 0; j < 4; ++j) d[lane + 64 * j] = __float2bfloat16(v[j]);
    }
}

// ---- big GEMM via bf16 MFMA, 2-phase double-buffered staging (T3-min pipeline) ----
// bmat bf16 [t][b][h*10+k]
__global__ __launch_bounds__(256) void gemm_b_mfma(const __hip_bfloat16* __restrict__ xb,
        const __hip_bfloat16* __restrict__ wb, const float* __restrict__ xninfo,
        __hip_bfloat16* __restrict__ bmat) {
    __shared__ __hip_bfloat16 As[2][4096];   // 2 x [128][32]
    __shared__ __hip_bfloat16 Bs[2][4096];
    int tid = threadIdx.x;
    int wid = tid >> 6, lane = tid & 63;
    int m0 = blockIdx.x * 128, n0 = blockIdx.y * 128;
    int wr = wid >> 1, wc = wid & 1;
    int srow = tid >> 2;
    int scol = (tid & 3) * 8;
    f32x4 acc[4][4] = {};

    const __hip_bfloat16* ga0 = xb + (size_t)(m0 + srow) * IN_DIM + scol;
    const __hip_bfloat16* gb0 = wb + (size_t)(n0 + srow) * IN_DIM + scol;

    // prologue: stage step 0 into buf 0
    #pragma unroll
    for (int half = 0; half < 2; ++half) {
        __builtin_amdgcn_global_load_lds((const GLOBAL_AS void*)(ga0 + half * 64 * IN_DIM),
            (LDS_AS void*)(&As[0][half * 2048 + wid * 512]), 16, 0, 0);
        __builtin_amdgcn_global_load_lds((const GLOBAL_AS void*)(gb0 + half * 64 * IN_DIM),
            (LDS_AS void*)(&Bs[0][half * 2048 + wid * 512]), 16, 0, 0);
    }
    __syncthreads();               // drains vmcnt -> buf0 ready

    int cur = 0;
    for (int step = 0; step < 8; ++step) {
        // issue NEXT tile's loads first (latency hides under ds_read+MFMA below)
        if (step < 7) {
            int kbn = (step + 1) * 32;
            #pragma unroll
            for (int half = 0; half < 2; ++half) {
                __builtin_amdgcn_global_load_lds((const GLOBAL_AS void*)(ga0 + half * 64 * IN_DIM + kbn),
                    (LDS_AS void*)(&As[cur ^ 1][half * 2048 + wid * 512]), 16, 0, 0);
                __builtin_amdgcn_global_load_lds((const GLOBAL_AS void*)(gb0 + half * 64 * IN_DIM + kbn),
                    (LDS_AS void*)(&Bs[cur ^ 1][half * 2048 + wid * 512]), 16, 0, 0);
            }
        }
        int seg = (lane >> 4) * 8;
        int rl = lane & 15;
        short8 a[4], b[4];
        #pragma unroll
        for (int m = 0; m < 4; ++m)
            a[m] = *(const short8*)(&As[cur][(wr * 64 + m * 16 + rl) * 32 + seg]);
        #pragma unroll
        for (int n = 0; n < 4; ++n)
            b[n] = *(const short8*)(&Bs[cur][(wc * 64 + n * 16 + rl) * 32 + seg]);
        #pragma unroll
        for (int m = 0; m < 4; ++m)
            #pragma unroll
            for (int n = 0; n < 4; ++n)
                acc[m][n] = __builtin_amdgcn_mfma_f32_16x16x32_bf16(a[m], b[n], acc[m][n], 0, 0, 0);
        __syncthreads();           // drains vmcnt(0) -> next buffer landed; cur free for restage
        cur ^= 1;
    }

    int col_l = lane & 15;
    int rseg = (lane >> 4) * 4;
    #pragma unroll
    for (int m = 0; m < 4; ++m) {
        int rbase = m0 + wr * 64 + m * 16 + rseg;
        float4 q0 = *(const float4*)(xninfo + 2 * rbase);
        float4 q1 = *(const float4*)(xninfo + 2 * rbase + 4);
        float nrm[4] = { q0.x, q0.z, q1.x, q1.z };
        float inv[4] = { q0.y, q0.w, q1.y, q1.w };
        #pragma unroll
        for (int n = 0; n < 4; ++n) {
            int col = n0 + wc * 64 + n * 16 + col_l;     // = h*10+k directly
            #pragma unroll
            for (int j = 0; j < 4; ++j) {
                float bv = nrm[j] * __expf(0.4f * acc[m][n][j] * inv[j] - 0.4f);
                bmat[(size_t)(rbase + j) * NKH + col] = __float2bfloat16(bv);
            }
        }
    }
}

// ---- Gram split-K partial, same 2-phase pipeline: Mpart[kz] = wb2[:,kz*160:+160] @ wb2^T ----
__global__ __launch_bounds__(256) void gram_partial(const __hip_bfloat16* __restrict__ wb2,
        float* __restrict__ Mpart) {
    __shared__ __hip_bfloat16 As[2][4096];
    __shared__ __hip_bfloat16 Bs[2][4096];
    int tid = threadIdx.x;
    int wid = tid >> 6, lane = tid & 63;
    int m0 = blockIdx.x * 128, n0 = blockIdx.y * 128;
    int kz = blockIdx.z;                  // 0..15, chunk of 160 = 5 steps of 32
    int wr = wid >> 1, wc = wid & 1;
    int srow = tid >> 2;
    int scol = (tid & 3) * 8;
    f32x4 acc[4][4] = {};

    const __hip_bfloat16* ga0 = wb2 + (size_t)(m0 + srow) * NKH + kz * 160 + scol;
    const __hip_bfloat16* gb0 = wb2 + (size_t)(n0 + srow) * NKH + kz * 160 + scol;

    #pragma unroll
    for (int half = 0; half < 2; ++half) {
        __builtin_amdgcn_global_load_lds((const GLOBAL_AS void*)(ga0 + half * 64 * NKH),
            (LDS_AS void*)(&As[0][half * 2048 + wid * 512]), 16, 0, 0);
        __builtin_amdgcn_global_load_lds((const GLOBAL_AS void*)(gb0 + half * 64 * NKH),
            (LDS_AS void*)(&Bs[0][half * 2048 + wid * 512]), 16, 0, 0);
    }
    __syncthreads();

    int cur = 0;
    for (int ks = 0; ks < 5; ++ks) {
        if (ks < 4) {
            int kbn = (ks + 1) * 32;
            #pragma unroll
            for (int half = 0; half < 2; ++half) {
                __builtin_amdgcn_global_load_lds((const GLOBAL_AS void*)(ga0 + half * 64 * NKH + kbn),
                    (LDS_AS void*)(&As[cur ^ 1][half * 2048 + wid * 512]), 16, 0, 0);
                __builtin_amdgcn_global_load_lds((const GLOBAL_AS void*)(gb0 + half * 64 * NKH + kbn),
                    (LDS_AS void*)(&Bs[cur ^ 1][half * 2048 + wid * 512]), 16, 0, 0);
            }
        }
        int seg = (lane >> 4) * 8;
        int rl = lane & 15;
        short8 a[4], b[4];
        #pragma unroll
        for (int m = 0; m < 4; ++m)
            a[m] = *(const short8*)(&As[cur][(wr * 64 + m * 16 + rl) * 32 + seg]);
        #pragma unroll
        for (int n = 0; n < 4; ++n)
            b[n] = *(const short8*)(&Bs[cur][(wc * 64 + n * 16 + rl) * 32 + seg]);
        #pragma unroll
        for (int m = 0; m < 4; ++m)
            #pragma unroll
            for (int n = 0; n < 4; ++n)
                acc[m][n] = __builtin_amdgcn_mfma_f32_16x16x32_bf16(a[m], b[n], acc[m][n], 0, 0, 0);
        __syncthreads();
        cur ^= 1;
    }

    float* dst = Mpart + (size_t)kz * 65536;
    int col_l = lane & 15;
    int rseg = (lane >> 4) * 4;
    #pragma unroll
    for (int m = 0; m < 4; ++m) {
        int rbase = m0 + wr * 64 + m * 16 + rseg;
        #pragma unroll
        for (int n = 0; n < 4; ++n) {
            int col = n0 + wc * 64 + n * 16 + col_l;
            #pragma unroll
            for (int j = 0; j < 4; ++j)
                dst[(size_t)(rbase + j) * H_DIM + col] = acc[m][n][j];
        }
    }
}

// ---- Gram finish: Mm = exp(0.4*sum_kz Mpart - 4), rsum[row] = row sum ----
__global__ __launch_bounds__(256) void gram_finish(const float* __restrict__ Mpart,
        float* __restrict__ Mm, float* __restrict__ rsum) {
    __shared__ float red[256];
    int r = blockIdx.x, c = threadIdx.x;
    float s = 0.f;
    #pragma unroll
    for (int kz = 0; kz < 16; ++kz)
        s += Mpart[(size_t)kz * 65536 + (size_t)r * H_DIM + c];
    float e = __expf(0.4f * s - 4.0f);
    Mm[(size_t)r * H_DIM + c] = e;
    red[c] = e;
    __syncthreads();
    #pragma unroll
    for (int st = 128; st > 0; st >>= 1) {
        if (c < st) red[c] += red[c + st];
        __syncthreads();
    }
    if (c == 0) rsum[r] = red[0];
}

// ---- shared power-iteration phase: fills vv (unit Perron vector), returns lam ----
__device__ __forceinline__ float power_phase(const float* __restrict__ Mm,
        const float* __restrict__ rsum, float* vv, float* red, int tid) {
    vv[tid] = rsum[tid];
    __syncthreads();
    float lam = 0.f;
    for (int it = 0; it <= NPOW; ++it) {
        float p = 0.f;
        #pragma unroll 8
        for (int g = 0; g < 256; ++g) p = fmaf(Mm[(size_t)g * 256 + tid], vv[g], p);
        __syncthreads();
        if (it < NPOW) {
            red[tid] = p * p;
            __syncthreads();
            #pragma unroll
            for (int st = 128; st > 0; st >>= 1) {
                if (tid < st) red[tid] += red[tid + st];
                __syncthreads();
            }
            float inv = rsqrtf(red[0]);
            __syncthreads();
            vv[tid] = p * inv;
            __syncthreads();
        } else {
            red[tid] = p * vv[tid];     // Rayleigh quotient (||v||=1)
            __syncthreads();
            #pragma unroll
            for (int st = 128; st > 0; st >>= 1) {
                if (tid < st) red[tid] += red[tid + st];
                __syncthreads();
            }
            lam = red[0];
            __syncthreads();
        }
    }
    return lam;
}

// ---- P2: E2 = E @ E, 16 blocks x 64x64 tile; embedded power phase; E from Mm on the fly ----
__global__ __launch_bounds__(256) void e2_kernel(const float* __restrict__ Mm,
        const float* __restrict__ rsum, float* __restrict__ E2g,
        __hip_bfloat16* __restrict__ e2b) {
    __shared__ __hip_bfloat16 EA[16384];   // [64][256] bf16, row-swizzled
    __shared__ __hip_bfloat16 EC[16384];
    __shared__ float vv[256];
    __shared__ float redl[256];
    int tid = threadIdx.x;
    int r0 = (blockIdx.x >> 2) * 64, c0 = (blockIdx.x & 3) * 64;
    float lam = power_phase(Mm, rsum, vv, redl, tid);
    float lm1 = lam - 1.f;
    char* pa = (char*)EA;
    char* pc = (char*)EC;
    for (int f = tid; f < 4096; f += 256) {
        int row = f >> 6, c4 = (f & 63) << 2;
        {
            int r = r0 + row;
            float4 mv = *(const float4*)(Mm + (size_t)r * 256 + c4);
            float vr = lm1 * vv[r];
            __hip_bfloat16 hb[4];
            hb[0] = __float2bfloat16(mv.x - ((r == c4 + 0) ? 1.f : 0.f) - vr * vv[c4 + 0]);
            hb[1] = __float2bfloat16(mv.y - ((r == c4 + 1) ? 1.f : 0.f) - vr * vv[c4 + 1]);
            hb[2] = __float2bfloat16(mv.z - ((r == c4 + 2) ? 1.f : 0.f) - vr * vv[c4 + 2]);
            hb[3] = __float2bfloat16(mv.w - ((r == c4 + 3) ? 1.f : 0.f) - vr * vv[c4 + 3]);
            *(short4*)(pa + row * 512 + ((c4 * 2) ^ ((row & 7) << 4))) = *(short4*)hb;
        }
        {
            int r = c0 + row;
            float4 mv = *(const float4*)(Mm + (size_t)r * 256 + c4);
            float vr = lm1 * vv[r];
            __hip_bfloat16 hb[4];
            hb[0] = __float2bfloat16(mv.x - ((r == c4 + 0) ? 1.f : 0.f) - vr * vv[c4 + 0]);
            hb[1] = __float2bfloat16(mv.y - ((r == c4 + 1) ? 1.f : 0.f) - vr * vv[c4 + 1]);
            hb[2] = __float2bfloat16(mv.z - ((r == c4 + 2) ? 1.f : 0.f) - vr * vv[c4 + 2]);
            hb[3] = __float2bfloat16(mv.w - ((r == c4 + 3) ? 1.f : 0.f) - vr * vv[c4 + 3]);
            *(short4*)(pc + row * 512 + ((c4 * 2) ^ ((row & 7) << 4))) = *(short4*)hb;
        }
    }
    __syncthreads();
    int wv = tid >> 6, lane = tid & 63;
    int rl = lane & 15, seg8 = (lane >> 4) * 8;
    f32x4 acc[4] = {};
    for (int kb = 0; kb < 256; kb += 32) {
        int row = wv * 16 + rl;
        short8 a = *(const short8*)(pa + row * 512 + (((kb + seg8) * 2) ^ ((rl & 7) << 4)));
        short8 b[4];
        #pragma unroll
        for (int n = 0; n < 4; ++n) {
            int rowb = n * 16 + rl;
            b[n] = *(const short8*)(pc + rowb * 512 + (((kb + seg8) * 2) ^ ((rl & 7) << 4)));
        }
        #pragma unroll
        for (int n = 0; n < 4; ++n)
            acc[n] = __builtin_amdgcn_mfma_f32_16x16x32_bf16(a, b[n], acc[n], 0, 0, 0);
    }
    int col_l = lane & 15, rseg = (lane >> 4) * 4;
    #pragma unroll
    for (int n = 0; n < 4; ++n) {
        #pragma unroll
        for (int j = 0; j < 4; ++j) {
            int r = r0 + wv * 16 + rseg + j;
            int c = c0 + n * 16 + col_l;
            size_t idx = (size_t)r * 256 + c;
            E2g[idx] = acc[n][j];
            e2b[idx] = __float2bfloat16(acc[n][j]);
        }
    }
}

// ---- P3: E3 = E @ E2; embedded power; lin = 1.5I - Mm/2 + (lm1/2+lfac) vv^T + 3/8 E2 - 5/16 E3
__global__ __launch_bounds__(256) void e3lin_kernel(const float* __restrict__ Mm,
        const float* __restrict__ rsum, const float* __restrict__ E2g,
        const __hip_bfloat16* __restrict__ e2b,
        float* __restrict__ lin, __hip_bfloat16* __restrict__ linb) {
    __shared__ __hip_bfloat16 EA[16384];   // [64][256] E rows, swizzled
    __shared__ __hip_bfloat16 EC[16384];   // [64][256] E2 rows (symmetric), swizzled
    __shared__ float vv[256];
    __shared__ float redl[256];
    int tid = threadIdx.x;
    int r0 = (blockIdx.x >> 2) * 64, c0 = (blockIdx.x & 3) * 64;
    float lam = power_phase(Mm, rsum, vv, redl, tid);
    float lm1 = lam - 1.f;
    float wfac = 0.5f * lm1 + (rsqrtf(lam) - 1.f);
    char* pa = (char*)EA;
    char* pc = (char*)EC;
    for (int f = tid; f < 4096; f += 256) {
        int row = f >> 6, c4 = (f & 63) << 2;
        int r = r0 + row;
        float4 mv = *(const float4*)(Mm + (size_t)r * 256 + c4);
        float vr = lm1 * vv[r];
        __hip_bfloat16 hb[4];
        hb[0] = __float2bfloat16(mv.x - ((r == c4 + 0) ? 1.f : 0.f) - vr * vv[c4 + 0]);
        hb[1] = __float2bfloat16(mv.y - ((r == c4 + 1) ? 1.f : 0.f) - vr * vv[c4 + 1]);
        hb[2] = __float2bfloat16(mv.z - ((r == c4 + 2) ? 1.f : 0.f) - vr * vv[c4 + 2]);
        hb[3] = __float2bfloat16(mv.w - ((r == c4 + 3) ? 1.f : 0.f) - vr * vv[c4 + 3]);
        *(short4*)(pa + row * 512 + ((c4 * 2) ^ ((row & 7) << 4))) = *(short4*)hb;
    }
    for (int f = tid; f < 2048; f += 256) {
        int row = f >> 5, c8 = (f & 31) << 3;
        short8 v8 = *(const short8*)(e2b + (size_t)(c0 + row) * 256 + c8);
        *(short8*)(pc + row * 512 + ((c8 * 2) ^ ((row & 7) << 4))) = v8;
    }
    __syncthreads();
    int wv = tid >> 6, lane = tid & 63;
    int rl = lane & 15, seg8 = (lane >> 4) * 8;
    f32x4 acc[4] = {};
    for (int kb = 0; kb < 256; kb += 32) {
        int row = wv * 16 + rl;
        short8 a = *(const short8*)(pa + row * 512 + (((kb + seg8) * 2) ^ ((rl & 7) << 4)));
        short8 b[4];
        #pragma unroll
        for (int n = 0; n < 4; ++n) {
            int rowb = n * 16 + rl;
            b[n] = *(const short8*)(pc + rowb * 512 + (((kb + seg8) * 2) ^ ((rl & 7) << 4)));
        }
        #pragma unroll
        for (int n = 0; n < 4; ++n)
            acc[n] = __builtin_amdgcn_mfma_f32_16x16x32_bf16(a, b[n], acc[n], 0, 0, 0);
    }
    int col_l = lane & 15, rseg = (lane >> 4) * 4;
    #pragma unroll
    for (int n = 0; n < 4; ++n) {
        #pragma unroll
        for (int j = 0; j < 4; ++j) {
            int r = r0 + wv * 16 + rseg + j;
            int c = c0 + n * 16 + col_l;
            size_t idx = (size_t)r * 256 + c;
            float lv = ((r == c) ? 1.5f : 0.f) - 0.5f * Mm[idx] + wfac * vv[r] * vv[c]
                     + 0.375f * E2g[idx] - 0.3125f * acc[n][j];
            lin[idx] = lv;
            linb[idx] = __float2bfloat16(lv);
        }
    }
}

// ---- megarec: 16 chunks x 32 outputs (warm-up 32) + fused out1 = c9 @ linb ----
// bmat layout [t][b][h*10+k]: thread h reads 20 contiguous bytes per step (dwordx4 + dword).
__global__ __launch_bounds__(256) void megarec(const __hip_bfloat16* __restrict__ bmat,
        const __hip_bfloat16* __restrict__ linb, float* __restrict__ out1,
        float* __restrict__ part, float* __restrict__ hxT) {
    __shared__ __hip_bfloat16 c9t[8192];   // [32][256] bf16, row-swizzled (16 KB)
    int tid = threadIdx.x;
    int s = blockIdx.x >> 5;               // 0..15
    int b = blockIdx.x & 31;
    int h = tid;
    int tout0 = s * 32;
    int t0 = (s == 0) ? 0 : tout0 - 32;
    int t1 = tout0 + 32;
    char* c9p = (char*)c9t;
    float c[10] = {};
    float s9 = 0.f;
    int4u v0; int v1;
    {
        const char* bp = (const char*)bmat + ((size_t)(t0 * B_DIM + b) * NKH + h * 10) * 2;
        v0 = *(const int4u*)bp;
        v1 = *(const int*)(bp + 16);
    }
    for (int t = t0; t < t1; ++t) {
        int tn = (t + 1 < t1) ? t + 1 : t;
        const char* bq = (const char*)bmat + ((size_t)(tn * B_DIM + b) * NKH + h * 10) * 2;
        int4u w0 = *(const int4u*)bq;
        int w1 = *(const int*)(bq + 16);
        float bt[10];
        bt[0] = bf_lo(v0.x); bt[1] = bf_hi(v0.x);
        bt[2] = bf_lo(v0.y); bt[3] = bf_hi(v0.y);
        bt[4] = bf_lo(v0.z); bt[5] = bf_hi(v0.z);
        bt[6] = bf_lo(v0.w); bt[7] = bf_hi(v0.w);
        bt[8] = bf_lo(v1);   bt[9] = bf_hi(v1);
        #pragma unroll
        for (int j = 9; j >= 1; --j) c[j] = 0.5f * c[j] + c[j - 1] * bt[j];
        c[0] = 0.5f * c[0] + bt[0];
        if (t >= tout0) {
            int tt = t - tout0;
            *(__hip_bfloat16*)(c9p + tt * 512 + ((h * 2) ^ ((tt & 7) << 4))) = __float2bfloat16(c[9]);
            s9 += c[9];
        }
        v0 = w0; v1 = w1;
    }
    part[(size_t)(s * B_DIM + b) * H_DIM + h] = s9;
    if (s == 15) {
        float* hp = hxT + (size_t)(b * H_DIM + h) * K_DIM;
        #pragma unroll
        for (int k = 0; k < 10; ++k) hp[k] = c[k];
    }
    __syncthreads();
    // out1 GEMM: [32 tt] x [256 h] @ linb -> out1[tout0+tt][b][g]; wave wid owns g in [wid*64,+64)
    int wid = tid >> 6, lane = tid & 63;
    int rl = lane & 15, seg8 = (lane >> 4) * 8;
    int col_l = lane & 15, rseg = (lane >> 4) * 4;
    f32x4 acc[2][4] = {};
    for (int kb = 0; kb < 256; kb += 32) {
        short8 a[2];
        #pragma unroll
        for (int m = 0; m < 2; ++m) {
            int row = m * 16 + rl;
            a[m] = *(const short8*)(c9p + row * 512 + (((kb + seg8) * 2) ^ ((row & 7) << 4)));
        }
        short8 bf[4];
        #pragma unroll
        for (int n = 0; n < 4; ++n)
            bf[n] = *(const short8*)(linb + (size_t)(wid * 64 + n * 16 + rl) * 256 + kb + seg8);
        #pragma unroll
        for (int m = 0; m < 2; ++m)
            #pragma unroll
            for (int n = 0; n < 4; ++n)
                acc[m][n] = __builtin_amdgcn_mfma_f32_16x16x32_bf16(a[m], bf[n], acc[m][n], 0, 0, 0);
    }
    #pragma unroll
    for (int m = 0; m < 2; ++m) {
        #pragma unroll
        for (int n = 0; n < 4; ++n) {
            int g = wid * 64 + n * 16 + col_l;
            #pragma unroll
            for (int j = 0; j < 4; ++j) {
                int tt = m * 16 + rseg + j;
                out1[((size_t)(tout0 + tt) * B_DIM + b) * H_DIM + g] = acc[m][n][j];
            }
        }
    }
}

// ---- recout: mean over T of c9 (from part) then out0 = mean @ lin, one block per b ----
__global__ __launch_bounds__(256) void recout_kernel(const float* __restrict__ part,
        const float* __restrict__ lin, float* __restrict__ out0) {
    __shared__ float mrow[256];
    int b = blockIdx.x, tid = threadIdx.x;
    float s = 0.f;
    #pragma unroll
    for (int j = 0; j < 16; ++j) s += part[(size_t)(j * B_DIM + b) * H_DIM + tid];
    mrow[tid] = s * (1.f / T_DIM);
    __syncthreads();
    float acc = 0.f;
    #pragma unroll 8
    for (int h = 0; h < H_DIM; ++h) acc = fmaf(mrow[h], lin[(size_t)h * H_DIM + tid], acc);
    out0[b * H_DIM + tid] = acc;
}

extern "C" void kernel_launch(void* const* d_in, const int* in_sizes, int n_in,
                              void* d_out, int out_size, void* d_ws, size_t ws_size,
                              hipStream_t stream) {
    const float* x = (const float*)d_in[0];
    const float* w = (const float*)d_in[1];
    float* out0 = (float*)d_out;                       // B*H
    float* out1 = out0 + (size_t)B_DIM * H_DIM;        // T*B*H
    float* hxT  = out1 + (size_t)TB * H_DIM;           // B*H*K

    char* ws = (char*)d_ws;
    __hip_bfloat16* wb   = (__hip_bfloat16*)(ws + 0);          // 1,310,720
    __hip_bfloat16* wb2  = (__hip_bfloat16*)(ws + 1310720);    // 1,310,720
    float* xninfo        = (float*)(ws + 2621440);             //   131,072
    float* Mm            = (float*)(ws + 2752512);             //   262,144
    float* rsum          = (float*)(ws + 3014656);             //     1,024
    float* E2g           = (float*)(ws + 3015680);             //   262,144
    __hip_bfloat16* e2b  = (__hip_bfloat16*)(ws + 3277824);    //   131,072
    float* lin           = (float*)(ws + 3408896);             //   262,144
    __hip_bfloat16* linb = (__hip_bfloat16*)(ws + 3671040);    //   131,072
    float* part          = (float*)(ws + 3802112);             //   524,288 (16 chunks)
    float* Mpart         = (float*)(ws + 4326400);             // 4,194,304
    __hip_bfloat16* xb   = (__hip_bfloat16*)(ws + 8520704);    // 8,388,608
    __hip_bfloat16* bmat = (__hip_bfloat16*)(ws + 16909312);   // 83,886,080 -> ~100.8 MB

    prep_kernel<<<dim3(4736), dim3(256), 0, stream>>>(w, x, wb, wb2, xninfo, xb);
    gemm_b_mfma<<<dim3(128, 20), dim3(256), 0, stream>>>(xb, wb, xninfo, bmat);
    gram_partial<<<dim3(2, 2, 16), dim3(256), 0, stream>>>(wb2, Mpart);
    gram_finish<<<dim3(256), dim3(256), 0, stream>>>(Mpart, Mm, rsum);
    e2_kernel<<<dim3(16), dim3(256), 0, stream>>>(Mm, rsum, E2g, e2b);
    e3lin_kernel<<<dim3(16), dim3(256), 0, stream>>>(Mm, rsum, E2g, e2b, lin, linb);
    megarec<<<dim3(512), dim3(256), 0, stream>>>(bmat, linb, out1, part, hxT);
    recout_kernel<<<dim3(32), dim3(256), 0, stream>>>(part, lin, out0);
}